// Round 3
// baseline (2745.861 us; speedup 1.0000x reference)
//
#include <hip/hip_runtime.h>

#define DIM 256
#define NEMB 8192
#define NQ 32768
#define OUT_Q_ELEMS 8388608   // 8*4096*256
#define CAP 128
#define MARGIN 3.0f

typedef __attribute__((ext_vector_type(8))) short short8;
typedef __attribute__((ext_vector_type(4))) float f32x4;
typedef unsigned int u32_as1 __attribute__((address_space(1)));
typedef unsigned int u32_as3 __attribute__((address_space(3)));

// fp32 -> bf16 round-to-nearest-even (no NaN handling; data is finite Gaussian)
__device__ __forceinline__ unsigned short f2bf(float f) {
    unsigned u = __float_as_uint(f);
    u += 0x7FFFu + ((u >> 16) & 1u);
    return (unsigned short)(u >> 16);
}
// order-preserving float<->uint encode for atomicMin
__device__ __forceinline__ unsigned encf(float f) {
    unsigned u = __float_as_uint(f);
    return u ^ (unsigned)((((int)u) >> 31) | 0x80000000);
}
__device__ __forceinline__ float decf(unsigned e) {
    unsigned u = (e >> 31) ? (e ^ 0x80000000u) : ~e;
    return __uint_as_float(u);
}
// async global->LDS, 16B per lane (dest = wave-uniform base + lane*16)
__device__ __forceinline__ void gll16(const void* g, void* l) {
    __builtin_amdgcn_global_load_lds((const u32_as1*)g, (u32_as3*)l, 16, 0, 0);
}

// ---------------------------------------------------------------------------
// init per-query running-min (encoded +inf = 0xFF800000, NOT 0xFFFFFFFF which
// decodes to NaN and kills every comparison) and candidate counts
// ---------------------------------------------------------------------------
__global__ void init_kernel(unsigned* __restrict__ rowmin, int* __restrict__ cnt) {
    int i = blockIdx.x * 256 + threadIdx.x;
    rowmin[i] = 0xFF800000u;  // encf(+inf)
    cnt[i] = 0;
}

// ---------------------------------------------------------------------------
// codebook squared norms: fp64 (selection anchor, k-ascending — must stay
// bit-identical to the round-1-passing arithmetic) + fp32 (MFMA epilogue)
// ---------------------------------------------------------------------------
__global__ void enorm_kernel(const float* __restrict__ embed,
                             double* __restrict__ ed, float* __restrict__ ef) {
    int j = blockIdx.x * 256 + threadIdx.x;
    double s = 0.0;
    for (int d = 0; d < DIM; ++d) {
        double v = (double)embed[(size_t)d * NEMB + j];
        s += v * v;
    }
    ed[j] = s;
    ef[j] = (float)s;
}

// ---------------------------------------------------------------------------
// embed^T fp32 [NEMB][DIM] for coalesced rescore/gather row reads (bit-exact copy)
// ---------------------------------------------------------------------------
__global__ void ebt_kernel(const float* __restrict__ embed, float* __restrict__ ebt) {
    int tid = blockIdx.x * 256 + threadIdx.x;  // NEMB*64 units
    int c = tid & (NEMB - 1);
    int d4 = tid >> 13;
#pragma unroll
    for (int u = 0; u < 4; ++u)
        ebt[(size_t)c * DIM + 4 * d4 + u] = embed[(size_t)(4 * d4 + u) * NEMB + c];
}

// ---------------------------------------------------------------------------
// X -> bf16, pre-tiled exactly as the GEMM's LDS A-image:
// Xc[mb][kc][c][mrow][j] ; q=128*mb+mrow, k=64*kc+8*c+j
// ---------------------------------------------------------------------------
__global__ void xc_kernel(const float* __restrict__ input,
                          unsigned short* __restrict__ Xc) {
    int tid = blockIdx.x * 256 + threadIdx.x;  // NQ*32 units
    int q = tid >> 5, kcc = tid & 31;
    const float* p = input + (size_t)q * DIM + kcc * 8;
    float4 a = *(const float4*)p;
    float4 b = *(const float4*)(p + 4);
    int mb = q >> 7, mrow = q & 127, kc = kcc >> 3, c = kcc & 7;
    short8 v;
    v[0] = (short)f2bf(a.x); v[1] = (short)f2bf(a.y);
    v[2] = (short)f2bf(a.z); v[3] = (short)f2bf(a.w);
    v[4] = (short)f2bf(b.x); v[5] = (short)f2bf(b.y);
    v[6] = (short)f2bf(b.z); v[7] = (short)f2bf(b.w);
    *(short8*)(Xc + (size_t)((((mb * 4 + kc) * 8) + c) * 128 + mrow) * 8) = v;
}

// ---------------------------------------------------------------------------
// E -> bf16, pre-tiled as the GEMM's LDS B-image (transpose happens here):
// Ec[nb][kc][c][nrow][j] = E[64kc+8c+j][128nb+nrow]
// ---------------------------------------------------------------------------
__global__ void ec_kernel(const float* __restrict__ embed,
                          unsigned short* __restrict__ Ec) {
    int tid = blockIdx.x * 256 + threadIdx.x;  // NEMB*32 units, n fast
    int n = tid & (NEMB - 1), kcc = tid >> 13;
    int nb = n >> 7, nrow = n & 127, kc = kcc >> 3, c = kcc & 7;
    short8 v;
#pragma unroll
    for (int j = 0; j < 8; ++j)
        v[j] = (short)f2bf(embed[(size_t)(kc * 64 + c * 8 + j) * NEMB + n]);
    *(short8*)(Ec + (size_t)((((nb * 4 + kc) * 8) + c) * 128 + nrow) * 8) = v;
}

// ---------------------------------------------------------------------------
// MFMA approx-distance GEMM + running-min + candidate collection.
// 128x128 block tile, 4 waves of 64x64 (4x4 frags of 16x16x32 bf16), K=256.
// dist~ = ||e||^2 - 2 x.e  (fp32).  Collect (q,c) with dist~ < min+MARGIN.
// Filter is conservative under stale rowmin (non-coherent L2 OK).
// ---------------------------------------------------------------------------
__global__ __launch_bounds__(256, 2) void mfma_argmin_kernel(
    const unsigned short* __restrict__ Xc, const unsigned short* __restrict__ Ec,
    const float* __restrict__ ef, unsigned* __restrict__ rowmin,
    int* __restrict__ cnt, unsigned short* __restrict__ cand) {
    __shared__ unsigned short As[8192];  // [c=4ks+q4][mrow][j]  16 KB
    __shared__ unsigned short Bs[8192];  // [c][nrow][j]          16 KB

    const int tid = threadIdx.x;
    const int w = tid >> 6, l = tid & 63;
    const int wm = w >> 1, wn = w & 1;
    const int l15 = l & 15, q4 = l >> 4;
    const int mb = blockIdx.x >> 6, nb = blockIdx.x & 63;  // nb fast -> Ec hot

    const unsigned short* xt = Xc + (size_t)mb * 4 * 8192;
    const unsigned short* et = Ec + (size_t)nb * 4 * 8192;

    f32x4 acc[4][4];
#pragma unroll
    for (int i = 0; i < 4; ++i)
#pragma unroll
        for (int j = 0; j < 4; ++j) acc[i][j] = (f32x4){0.f, 0.f, 0.f, 0.f};

    for (int kc = 0; kc < 4; ++kc) {
        __syncthreads();
#pragma unroll
        for (int s = 0; s < 4; ++s) {  // wave w stages 4 KB of A and 4 KB of B
            int t = w * 4 + s;
            gll16(xt + kc * 8192 + t * 512 + l * 8, &As[t * 512 + l * 8]);
            gll16(et + kc * 8192 + t * 512 + l * 8, &Bs[t * 512 + l * 8]);
        }
        __syncthreads();
#pragma unroll
        for (int ks = 0; ks < 2; ++ks) {
            short8 af[4], bf[4];
#pragma unroll
            for (int i = 0; i < 4; ++i)
                af[i] = *(const short8*)&As[((ks * 4 + q4) * 128 + wm * 64 + i * 16 + l15) * 8];
#pragma unroll
            for (int j = 0; j < 4; ++j)
                bf[j] = *(const short8*)&Bs[((ks * 4 + q4) * 128 + wn * 64 + j * 16 + l15) * 8];
#pragma unroll
            for (int i = 0; i < 4; ++i)
#pragma unroll
                for (int j = 0; j < 4; ++j)
                    acc[i][j] = __builtin_amdgcn_mfma_f32_16x16x32_bf16(
                        af[i], bf[j], acc[i][j], 0, 0, 0);
        }
    }

    // ---- epilogue: dist~, per-row min (butterfly over the 16 col-lanes),
    //      global running min, margin collection.
    const int col0 = nb * 128 + wn * 64 + l15;
    float en[4];
#pragma unroll
    for (int j = 0; j < 4; ++j) en[j] = ef[col0 + 16 * j];
#pragma unroll
    for (int i = 0; i < 4; ++i)
#pragma unroll
        for (int j = 0; j < 4; ++j)
#pragma unroll
            for (int r = 0; r < 4; ++r)
                acc[i][j][r] = en[j] - 2.0f * acc[i][j][r];  // dist~

    float pm[4][4];
#pragma unroll
    for (int i = 0; i < 4; ++i)
#pragma unroll
        for (int r = 0; r < 4; ++r) {
            float m0 = fminf(acc[i][0][r], acc[i][1][r]);
            float m1 = fminf(acc[i][2][r], acc[i][3][r]);
            pm[i][r] = fminf(m0, m1);
        }
#pragma unroll
    for (int step = 1; step < 16; step <<= 1)
#pragma unroll
        for (int i = 0; i < 4; ++i)
#pragma unroll
            for (int r = 0; r < 4; ++r)
                pm[i][r] = fminf(pm[i][r], __shfl_xor(pm[i][r], step, 64));

    float gm[4][4];
#pragma unroll
    for (int i = 0; i < 4; ++i)
#pragma unroll
        for (int r = 0; r < 4; ++r) {
            int row = mb * 128 + wm * 64 + i * 16 + q4 * 4 + r;
            float g = decf(rowmin[row]);  // stale-conservative (>= true min)
            if (pm[i][r] < g && l15 == 0) atomicMin(&rowmin[row], encf(pm[i][r]));
            gm[i][r] = fminf(g, pm[i][r]) + MARGIN;
        }
#pragma unroll
    for (int i = 0; i < 4; ++i)
#pragma unroll
        for (int r = 0; r < 4; ++r) {
        const int row = mb * 128 + wm * 64 + i * 16 + q4 * 4 + r;
#pragma unroll
        for (int j = 0; j < 4; ++j) {
            if (acc[i][j][r] < gm[i][r]) {
                int slot = atomicAdd(&cnt[row], 1);
                if (slot < CAP)
                    cand[(size_t)row * CAP + slot] = (unsigned short)(col0 + 16 * j);
            }
        }
    }
}

// ---------------------------------------------------------------------------
// Rescore with the EXACT round-1 (reference-matching, proven-passing) metric:
// fp32 k-ascending single-accumulator fmaf dot, dist = ed[c] - 2*(double)dot,
// argmin with smallest-index tie-break. One wave per query, lane-per-candidate.
// Fallback: full 8192-code scan if candidate list unusable (never in practice).
// Fused with quantize gather + fp64 diff partial.
// ---------------------------------------------------------------------------
__global__ __launch_bounds__(256) void rescore_kernel(
    const float* __restrict__ input, const float* __restrict__ ebt,
    const double* __restrict__ ed, const int* __restrict__ cnt,
    const unsigned short* __restrict__ cand, float* __restrict__ out_q,
    float* __restrict__ out_idx, double* __restrict__ partials) {
    __shared__ float Xs[4][DIM];
    const int w = threadIdx.x >> 6, l = threadIdx.x & 63;
    const int q = blockIdx.x * 4 + w;

    float4 xf = *(const float4*)(input + (size_t)q * DIM + 4 * l);
    *(float4*)&Xs[w][4 * l] = xf;
    __syncthreads();

    const int n = cnt[q];
    double bd = 1e300;
    int bc = 0x7FFFFFFF;

    if (n >= 1 && n <= CAP) {
        for (int s = l; s < n; s += 64) {
            const int c = cand[(size_t)q * CAP + s];
            const float* ep = ebt + (size_t)c * DIM;
            float acc = 0.0f;
            for (int k4 = 0; k4 < DIM / 4; ++k4) {  // k ascending: replica order
                float4 e4 = *(const float4*)(ep + 4 * k4);
                float4 x4 = *(const float4*)&Xs[w][4 * k4];
                acc = fmaf(x4.x, e4.x, acc);
                acc = fmaf(x4.y, e4.y, acc);
                acc = fmaf(x4.z, e4.z, acc);
                acc = fmaf(x4.w, e4.w, acc);
            }
            double d = ed[c] - 2.0 * (double)acc;
            if (d < bd || (d == bd && c < bc)) { bd = d; bc = c; }
        }
    } else {  // overflow / impossible-count insurance: exact full scan
        for (int c = l; c < NEMB; c += 64) {
            const float* ep = ebt + (size_t)c * DIM;
            float acc = 0.0f;
            for (int k4 = 0; k4 < DIM / 4; ++k4) {
                float4 e4 = *(const float4*)(ep + 4 * k4);
                float4 x4 = *(const float4*)&Xs[w][4 * k4];
                acc = fmaf(x4.x, e4.x, acc);
                acc = fmaf(x4.y, e4.y, acc);
                acc = fmaf(x4.z, e4.z, acc);
                acc = fmaf(x4.w, e4.w, acc);
            }
            double d = ed[c] - 2.0 * (double)acc;
            if (d < bd || (d == bd && c < bc)) { bd = d; bc = c; }
        }
    }
    // wave-wide argmin butterfly (tie-break: smallest index) -> all lanes agree
#pragma unroll
    for (int off = 1; off < 64; off <<= 1) {
        double od = __shfl_xor(bd, off, 64);
        int oc = __shfl_xor(bc, off, 64);
        if (od < bd || (od == bd && oc < bc)) { bd = od; bc = oc; }
    }

    float4 e4 = *(const float4*)(ebt + (size_t)bc * DIM + 4 * l);
    *(float4*)(out_q + (size_t)q * DIM + 4 * l) = e4;
    float d0 = e4.x - xf.x, d1 = e4.y - xf.y;
    float d2 = e4.z - xf.z, d3 = e4.w - xf.w;
    double dd = (double)d0 * d0 + (double)d1 * d1 +
                (double)d2 * d2 + (double)d3 * d3;
#pragma unroll
    for (int off = 1; off < 64; off <<= 1) dd += __shfl_xor(dd, off, 64);
    if (l == 0) {
        out_idx[q] = (float)bc;
        partials[q] = dd;
    }
}

// ---------------------------------------------------------------------------
// reduce partials -> mean -> diff
// ---------------------------------------------------------------------------
__global__ void diff_kernel(const double* __restrict__ partials,
                            float* __restrict__ out_diff) {
    const int t = threadIdx.x;
    double s = 0.0;
    for (int i = t; i < NQ; i += 256) s += partials[i];
#pragma unroll
    for (int off = 32; off >= 1; off >>= 1) s += __shfl_down(s, off, 64);
    __shared__ double red[4];
    if ((t & 63) == 0) red[t >> 6] = s;
    __syncthreads();
    if (t == 0)
        out_diff[0] = (float)((red[0] + red[1] + red[2] + red[3]) /
                              (double)OUT_Q_ELEMS);
}

extern "C" void kernel_launch(void* const* d_in, const int* in_sizes, int n_in,
                              void* d_out, int out_size, void* d_ws,
                              size_t ws_size, hipStream_t stream) {
    const float* input = (const float*)d_in[0];  // [8,4096,256] fp32
    const float* embed = (const float*)d_in[1];  // [256,8192]  fp32

    float* out_q    = (float*)d_out;             // quantize
    float* out_diff = out_q + OUT_Q_ELEMS;       // diff scalar
    float* out_idx  = out_diff + 1;              // embed_ind (as float)

    char* p = (char*)d_ws;
    unsigned short* Ec  = (unsigned short*)(p);                    //  4 MB
    unsigned short* Xc  = (unsigned short*)(p + 4194304);          // 16 MB
    float*          ebt = (float*)(p + 20971520);                  //  8 MB
    double*         ed  = (double*)(p + 29360128);                 // 64 KB
    float*          ef  = (float*)(p + 29425664);                  // 32 KB
    unsigned*       rowmin = (unsigned*)(p + 29458432);            // 128 KB
    int*            cnt = (int*)(p + 29589504);                    // 128 KB
    double*         partials = (double*)(p + 29720576);            // 256 KB
    unsigned short* cand = (unsigned short*)(p + 29982720);        //  8 MB

    hipLaunchKernelGGL(init_kernel, dim3(NQ / 256), dim3(256), 0, stream,
                       rowmin, cnt);
    hipLaunchKernelGGL(enorm_kernel, dim3(NEMB / 256), dim3(256), 0, stream,
                       embed, ed, ef);
    hipLaunchKernelGGL(ebt_kernel, dim3(NEMB * 64 / 256), dim3(256), 0, stream,
                       embed, ebt);
    hipLaunchKernelGGL(xc_kernel, dim3(NQ * 32 / 256), dim3(256), 0, stream,
                       input, Xc);
    hipLaunchKernelGGL(ec_kernel, dim3(NEMB * 32 / 256), dim3(256), 0, stream,
                       embed, Ec);
    hipLaunchKernelGGL(mfma_argmin_kernel, dim3((NQ / 128) * (NEMB / 128)),
                       dim3(256), 0, stream, Xc, Ec, ef, rowmin, cnt, cand);
    hipLaunchKernelGGL(rescore_kernel, dim3(NQ / 4), dim3(256), 0, stream,
                       input, ebt, ed, cnt, cand, out_q, out_idx, partials);
    hipLaunchKernelGGL(diff_kernel, dim3(1), dim3(256), 0, stream,
                       partials, out_diff);
}

// Round 4
// 1284.484 us; speedup vs baseline: 2.1377x; 2.1377x over previous
//
#include <hip/hip_runtime.h>

#define DIM 256
#define NEMB 8192
#define NQ 32768
#define OUT_Q_ELEMS 8388608   // 8*4096*256
#define NSEG 4
#define CAP_SEG 24
#define MARGIN 3.0f

typedef __attribute__((ext_vector_type(8))) short short8;
typedef __attribute__((ext_vector_type(4))) float f32x4;
typedef unsigned int u32_as1 __attribute__((address_space(1)));
typedef unsigned int u32_as3 __attribute__((address_space(3)));

// fp32 -> bf16 round-to-nearest-even
__device__ __forceinline__ unsigned short f2bf(float f) {
    unsigned u = __float_as_uint(f);
    u += 0x7FFFu + ((u >> 16) & 1u);
    return (unsigned short)(u >> 16);
}
// async global->LDS, 16B per lane (dest = wave-uniform base + lane*16)
__device__ __forceinline__ void gll16(const void* g, void* l) {
    __builtin_amdgcn_global_load_lds((const u32_as1*)g, (u32_as3*)l, 16, 0, 0);
}

// ---------------------------------------------------------------------------
// zero per-(row,seg) candidate counts
// ---------------------------------------------------------------------------
__global__ void init_kernel(int* __restrict__ cnt) {
    cnt[blockIdx.x * 256 + threadIdx.x] = 0;
}

// ---------------------------------------------------------------------------
// codebook squared norms: fp64 (selection anchor, k-ascending, bit-stable)
// + fp32 (MFMA epilogue)
// ---------------------------------------------------------------------------
__global__ void enorm_kernel(const float* __restrict__ embed,
                             double* __restrict__ ed, float* __restrict__ ef) {
    int j = blockIdx.x * 256 + threadIdx.x;
    double s = 0.0;
    for (int d = 0; d < DIM; ++d) {
        double v = (double)embed[(size_t)d * NEMB + j];
        s += v * v;
    }
    ed[j] = s;
    ef[j] = (float)s;
}

// ---------------------------------------------------------------------------
// embed^T fp32 [NEMB][DIM], LDS-tiled transpose (coalesced both sides).
// 64x64 tiles; +1 pad kills bank conflicts. Bit-exact copy.
// ---------------------------------------------------------------------------
__global__ void ebt_kernel(const float* __restrict__ embed, float* __restrict__ ebt) {
    __shared__ float t[64][65];
    const int bx = blockIdx.x & 127;   // c-tile
    const int by = blockIdx.x >> 7;    // d-tile (0..3)
    const int tx = threadIdx.x & 63, ty = threadIdx.x >> 6;
#pragma unroll
    for (int i = 0; i < 16; ++i) {
        int d = by * 64 + ty * 16 + i;
        t[ty * 16 + i][tx] = embed[(size_t)d * NEMB + bx * 64 + tx];
    }
    __syncthreads();
#pragma unroll
    for (int i = 0; i < 16; ++i) {
        int c = bx * 64 + ty * 16 + i;
        ebt[(size_t)c * DIM + by * 64 + tx] = t[tx][ty * 16 + i];
    }
}

// ---------------------------------------------------------------------------
// X -> bf16, pre-tiled as the GEMM's LDS A-image:
// Xc[mb][kc][c][mrow][j] ; q=128*mb+mrow, k=64*kc+8*c+j
// ---------------------------------------------------------------------------
__global__ void xc_kernel(const float* __restrict__ input,
                          unsigned short* __restrict__ Xc) {
    int tid = blockIdx.x * 256 + threadIdx.x;  // NQ*32 units
    int q = tid >> 5, kcc = tid & 31;
    const float* p = input + (size_t)q * DIM + kcc * 8;
    float4 a = *(const float4*)p;
    float4 b = *(const float4*)(p + 4);
    int mb = q >> 7, mrow = q & 127, kc = kcc >> 3, c = kcc & 7;
    short8 v;
    v[0] = (short)f2bf(a.x); v[1] = (short)f2bf(a.y);
    v[2] = (short)f2bf(a.z); v[3] = (short)f2bf(a.w);
    v[4] = (short)f2bf(b.x); v[5] = (short)f2bf(b.y);
    v[6] = (short)f2bf(b.z); v[7] = (short)f2bf(b.w);
    *(short8*)(Xc + (size_t)((((mb * 4 + kc) * 8) + c) * 128 + mrow) * 8) = v;
}

// ---------------------------------------------------------------------------
// E -> bf16, pre-tiled as the GEMM's LDS B-image:
// Ec[nb][kc][c][nrow][j] = E[64kc+8c+j][128nb+nrow]
// ---------------------------------------------------------------------------
__global__ void ec_kernel(const float* __restrict__ embed,
                          unsigned short* __restrict__ Ec) {
    int tid = blockIdx.x * 256 + threadIdx.x;  // NEMB*32 units, n fast
    int n = tid & (NEMB - 1), kcc = tid >> 13;
    int nb = n >> 7, nrow = n & 127, kc = kcc >> 3, c = kcc & 7;
    short8 v;
#pragma unroll
    for (int j = 0; j < 8; ++j)
        v[j] = (short)f2bf(embed[(size_t)(kc * 64 + c * 8 + j) * NEMB + n]);
    *(short8*)(Ec + (size_t)((((nb * 4 + kc) * 8) + c) * 128 + nrow) * 8) = v;
}

// ---------------------------------------------------------------------------
// MFMA argmin, self-contained per block: block = (mb, seg) owns 128 rows x
// 2048 codes (16 tiles of 128), loops tiles internally. Running row-min in
// registers (per-wave, conservative); slot allocation via LDS atomics;
// private cand segment per (row,seg). NO global atomics.
// ---------------------------------------------------------------------------
__global__ __launch_bounds__(256, 4) void mfma_argmin_kernel(
    const unsigned short* __restrict__ Xc, const unsigned short* __restrict__ Ec,
    const float* __restrict__ ef, int* __restrict__ cnt,
    unsigned short* __restrict__ cand) {
    __shared__ unsigned short As[8192];  // 16 KB, one kc chunk of A
    __shared__ unsigned short Bs[8192];  // 16 KB, one kc chunk of B
    __shared__ unsigned lcnt[128];

    const int tid = threadIdx.x;
    const int w = tid >> 6, l = tid & 63;
    const int wm = w >> 1, wn = w & 1;
    const int l15 = l & 15, q4 = l >> 4;
    const int mb = blockIdx.x & 255;   // mb fast: concurrent blocks share seg
    const int seg = blockIdx.x >> 8;

    const unsigned short* xt = Xc + (size_t)mb * 4 * 8192;

    if (tid < 128) lcnt[tid] = 0;

    float rm[4][4];  // per-wave running row-min (64-col half): conservative
#pragma unroll
    for (int i = 0; i < 4; ++i)
#pragma unroll
        for (int r = 0; r < 4; ++r) rm[i][r] = 1e30f;

    for (int t16 = 0; t16 < 16; ++t16) {
        const int nb = seg * 16 + t16;
        const unsigned short* et = Ec + (size_t)nb * 4 * 8192;
        const int col0 = nb * 128 + wn * 64 + l15;
        float en[4];
#pragma unroll
        for (int j = 0; j < 4; ++j) en[j] = ef[col0 + 16 * j];  // early issue

        f32x4 acc[4][4];
#pragma unroll
        for (int i = 0; i < 4; ++i)
#pragma unroll
            for (int j = 0; j < 4; ++j) acc[i][j] = (f32x4){0.f, 0.f, 0.f, 0.f};

        for (int kc = 0; kc < 4; ++kc) {
            __syncthreads();
#pragma unroll
            for (int s = 0; s < 4; ++s) {  // wave stages 4 KB of A + 4 KB of B
                int t = w * 4 + s;
                gll16(xt + kc * 8192 + t * 512 + l * 8, &As[t * 512 + l * 8]);
                gll16(et + kc * 8192 + t * 512 + l * 8, &Bs[t * 512 + l * 8]);
            }
            __syncthreads();
#pragma unroll
            for (int ks = 0; ks < 2; ++ks) {
                short8 af[4], bf[4];
#pragma unroll
                for (int i = 0; i < 4; ++i)
                    af[i] = *(const short8*)&As[((ks * 4 + q4) * 128 + wm * 64 + i * 16 + l15) * 8];
#pragma unroll
                for (int j = 0; j < 4; ++j)
                    bf[j] = *(const short8*)&Bs[((ks * 4 + q4) * 128 + wn * 64 + j * 16 + l15) * 8];
#pragma unroll
                for (int i = 0; i < 4; ++i)
#pragma unroll
                    for (int j = 0; j < 4; ++j)
                        acc[i][j] = __builtin_amdgcn_mfma_f32_16x16x32_bf16(
                            af[i], bf[j], acc[i][j], 0, 0, 0);
            }
        }

        // ---- epilogue: dist~, register running-min, LDS-slot collection
#pragma unroll
        for (int i = 0; i < 4; ++i)
#pragma unroll
            for (int j = 0; j < 4; ++j)
#pragma unroll
                for (int r = 0; r < 4; ++r)
                    acc[i][j][r] = en[j] - 2.0f * acc[i][j][r];  // dist~

#pragma unroll
        for (int i = 0; i < 4; ++i)
#pragma unroll
            for (int r = 0; r < 4; ++r) {
                float m = fminf(fminf(acc[i][0][r], acc[i][1][r]),
                                fminf(acc[i][2][r], acc[i][3][r]));
#pragma unroll
                for (int step = 1; step < 16; step <<= 1)
                    m = fminf(m, __shfl_xor(m, step, 64));  // row-min this tile
                rm[i][r] = fminf(rm[i][r], m);
                const float thr = rm[i][r] + MARGIN;
                const int row128 = wm * 64 + i * 16 + q4 * 4 + r;
#pragma unroll
                for (int j = 0; j < 4; ++j) {
                    if (acc[i][j][r] < thr) {
                        unsigned slot = atomicAdd(&lcnt[row128], 1u);
                        if (slot < CAP_SEG)
                            cand[((size_t)(mb * 128 + row128) * NSEG + seg) * CAP_SEG + slot] =
                                (unsigned short)(col0 + 16 * j);
                    }
                }
            }
    }
    __syncthreads();
    if (tid < 128) cnt[(mb * 128 + tid) * NSEG + seg] = (int)lcnt[tid];
}

// ---------------------------------------------------------------------------
// Rescore with the EXACT proven-passing metric: fp32 k-ascending single-acc
// fmaf dot, dist = ed[c] - 2*(double)dot, argmin with smallest-index
// tie-break (order-independent). Merges the 4 per-seg candidate lists.
// Fallback full scan only if a seg overflowed (never in practice).
// Fused with quantize gather + fp64 diff partial. One wave per query.
// ---------------------------------------------------------------------------
__global__ __launch_bounds__(256) void rescore_kernel(
    const float* __restrict__ input, const float* __restrict__ ebt,
    const double* __restrict__ ed, const int* __restrict__ cnt,
    const unsigned short* __restrict__ cand, float* __restrict__ out_q,
    float* __restrict__ out_idx, double* __restrict__ partials) {
    __shared__ float Xs[4][DIM];
    const int w = threadIdx.x >> 6, l = threadIdx.x & 63;
    const int q = blockIdx.x * 4 + w;

    float4 xf = *(const float4*)(input + (size_t)q * DIM + 4 * l);
    *(float4*)&Xs[w][4 * l] = xf;
    __syncthreads();

    int ns[NSEG];
    bool ok = true;
#pragma unroll
    for (int s4 = 0; s4 < NSEG; ++s4) {
        ns[s4] = cnt[q * NSEG + s4];
        if (ns[s4] > CAP_SEG) ok = false;
    }

    double bd = 1e300;
    int bc = 0x7FFFFFFF;
    if (ok) {
#pragma unroll
        for (int s4 = 0; s4 < NSEG; ++s4) {
            for (int s = l; s < ns[s4]; s += 64) {
                const int c = cand[((size_t)q * NSEG + s4) * CAP_SEG + s];
                const float* ep = ebt + (size_t)c * DIM;
                float acc = 0.0f;
                for (int k4 = 0; k4 < DIM / 4; ++k4) {  // k ascending: replica
                    float4 e4 = *(const float4*)(ep + 4 * k4);
                    float4 x4 = *(const float4*)&Xs[w][4 * k4];
                    acc = fmaf(x4.x, e4.x, acc);
                    acc = fmaf(x4.y, e4.y, acc);
                    acc = fmaf(x4.z, e4.z, acc);
                    acc = fmaf(x4.w, e4.w, acc);
                }
                double d = ed[c] - 2.0 * (double)acc;
                if (d < bd || (d == bd && c < bc)) { bd = d; bc = c; }
            }
        }
    } else {  // overflow insurance: exact full scan
        for (int c = l; c < NEMB; c += 64) {
            const float* ep = ebt + (size_t)c * DIM;
            float acc = 0.0f;
            for (int k4 = 0; k4 < DIM / 4; ++k4) {
                float4 e4 = *(const float4*)(ep + 4 * k4);
                float4 x4 = *(const float4*)&Xs[w][4 * k4];
                acc = fmaf(x4.x, e4.x, acc);
                acc = fmaf(x4.y, e4.y, acc);
                acc = fmaf(x4.z, e4.z, acc);
                acc = fmaf(x4.w, e4.w, acc);
            }
            double d = ed[c] - 2.0 * (double)acc;
            if (d < bd || (d == bd && c < bc)) { bd = d; bc = c; }
        }
    }
#pragma unroll
    for (int off = 1; off < 64; off <<= 1) {
        double od = __shfl_xor(bd, off, 64);
        int oc = __shfl_xor(bc, off, 64);
        if (od < bd || (od == bd && oc < bc)) { bd = od; bc = oc; }
    }

    float4 e4 = *(const float4*)(ebt + (size_t)bc * DIM + 4 * l);
    *(float4*)(out_q + (size_t)q * DIM + 4 * l) = e4;
    float d0 = e4.x - xf.x, d1 = e4.y - xf.y;
    float d2 = e4.z - xf.z, d3 = e4.w - xf.w;
    double dd = (double)d0 * d0 + (double)d1 * d1 +
                (double)d2 * d2 + (double)d3 * d3;
#pragma unroll
    for (int off = 1; off < 64; off <<= 1) dd += __shfl_xor(dd, off, 64);
    if (l == 0) {
        out_idx[q] = (float)bc;
        partials[q] = dd;
    }
}

// ---------------------------------------------------------------------------
// reduce partials -> mean -> diff
// ---------------------------------------------------------------------------
__global__ void diff_kernel(const double* __restrict__ partials,
                            float* __restrict__ out_diff) {
    const int t = threadIdx.x;
    double s = 0.0;
    for (int i = t; i < NQ; i += 256) s += partials[i];
#pragma unroll
    for (int off = 32; off >= 1; off >>= 1) s += __shfl_down(s, off, 64);
    __shared__ double red[4];
    if ((t & 63) == 0) red[t >> 6] = s;
    __syncthreads();
    if (t == 0)
        out_diff[0] = (float)((red[0] + red[1] + red[2] + red[3]) /
                              (double)OUT_Q_ELEMS);
}

extern "C" void kernel_launch(void* const* d_in, const int* in_sizes, int n_in,
                              void* d_out, int out_size, void* d_ws,
                              size_t ws_size, hipStream_t stream) {
    const float* input = (const float*)d_in[0];  // [8,4096,256] fp32
    const float* embed = (const float*)d_in[1];  // [256,8192]  fp32

    float* out_q    = (float*)d_out;             // quantize
    float* out_diff = out_q + OUT_Q_ELEMS;       // diff scalar
    float* out_idx  = out_diff + 1;              // embed_ind (as float)

    char* p = (char*)d_ws;
    unsigned short* Ec  = (unsigned short*)(p);                 //  4 MB
    unsigned short* Xc  = (unsigned short*)(p + 4194304);       // 16 MB
    float*          ebt = (float*)(p + 20971520);               //  8 MB
    double*         ed  = (double*)(p + 29360128);              // 64 KB
    float*          ef  = (float*)(p + 29425664);               // 32 KB
    int*            cnt = (int*)(p + 29458432);                 // 512 KB
    double*         partials = (double*)(p + 29982720);         // 256 KB
    unsigned short* cand = (unsigned short*)(p + 30244864);     //  6 MB

    hipLaunchKernelGGL(init_kernel, dim3(NQ * NSEG / 256), dim3(256), 0, stream,
                       cnt);
    hipLaunchKernelGGL(enorm_kernel, dim3(NEMB / 256), dim3(256), 0, stream,
                       embed, ed, ef);
    hipLaunchKernelGGL(ebt_kernel, dim3((NEMB / 64) * (DIM / 64)), dim3(256),
                       0, stream, embed, ebt);
    hipLaunchKernelGGL(xc_kernel, dim3(NQ * 32 / 256), dim3(256), 0, stream,
                       input, Xc);
    hipLaunchKernelGGL(ec_kernel, dim3(NEMB * 32 / 256), dim3(256), 0, stream,
                       embed, Ec);
    hipLaunchKernelGGL(mfma_argmin_kernel, dim3((NQ / 128) * NSEG), dim3(256),
                       0, stream, Xc, Ec, ef, cnt, cand);
    hipLaunchKernelGGL(rescore_kernel, dim3(NQ / 4), dim3(256), 0, stream,
                       input, ebt, ed, cnt, cand, out_q, out_idx, partials);
    hipLaunchKernelGGL(diff_kernel, dim3(1), dim3(256), 0, stream,
                       partials, out_diff);
}

// Round 5
// 709.980 us; speedup vs baseline: 3.8675x; 1.8092x over previous
//
#include <hip/hip_runtime.h>

#define DIM 256
#define NEMB 8192
#define NQ 32768
#define OUT_Q_ELEMS 8388608   // 8*4096*256
#define NSEG 4
#define SEG_CODES 2048
#define CAP_SEG 24
#define MARGIN 1.0f

typedef __attribute__((ext_vector_type(8))) short short8;
typedef __attribute__((ext_vector_type(4))) float f32x4;
typedef unsigned int u32_as1 __attribute__((address_space(1)));
typedef unsigned int u32_as3 __attribute__((address_space(3)));

// fp32 -> bf16 round-to-nearest-even
__device__ __forceinline__ unsigned short f2bf(float f) {
    unsigned u = __float_as_uint(f);
    u += 0x7FFFu + ((u >> 16) & 1u);
    return (unsigned short)(u >> 16);
}
// async global->LDS, 16B per lane (dest = wave-uniform base + lane*16)
__device__ __forceinline__ void gll16(const void* g, void* l) {
    __builtin_amdgcn_global_load_lds((const u32_as1*)g, (u32_as3*)l, 16, 0, 0);
}

// The EXACT proven-passing metric: fp32 k-ascending single-accumulator fmaf
// chain, dist = ed[c] - 2*(double)dot. 2-deep pipelined 64B loads.
__device__ __forceinline__ double chain_dist(const float* __restrict__ ep,
                                             const float* __restrict__ xs,
                                             double edc) {
    float acc = 0.0f;
    float4 e0 = *(const float4*)(ep);
    float4 e1 = *(const float4*)(ep + 4);
    float4 e2 = *(const float4*)(ep + 8);
    float4 e3 = *(const float4*)(ep + 12);
#pragma unroll
    for (int kk = 0; kk < 15; ++kk) {
        const int k = kk * 16;
        float4 n0 = *(const float4*)(ep + k + 16);
        float4 n1 = *(const float4*)(ep + k + 20);
        float4 n2 = *(const float4*)(ep + k + 24);
        float4 n3 = *(const float4*)(ep + k + 28);
        float4 x0 = *(const float4*)(xs + k);
        float4 x1 = *(const float4*)(xs + k + 4);
        float4 x2 = *(const float4*)(xs + k + 8);
        float4 x3 = *(const float4*)(xs + k + 12);
        acc = fmaf(x0.x, e0.x, acc); acc = fmaf(x0.y, e0.y, acc);
        acc = fmaf(x0.z, e0.z, acc); acc = fmaf(x0.w, e0.w, acc);
        acc = fmaf(x1.x, e1.x, acc); acc = fmaf(x1.y, e1.y, acc);
        acc = fmaf(x1.z, e1.z, acc); acc = fmaf(x1.w, e1.w, acc);
        acc = fmaf(x2.x, e2.x, acc); acc = fmaf(x2.y, e2.y, acc);
        acc = fmaf(x2.z, e2.z, acc); acc = fmaf(x2.w, e2.w, acc);
        acc = fmaf(x3.x, e3.x, acc); acc = fmaf(x3.y, e3.y, acc);
        acc = fmaf(x3.z, e3.z, acc); acc = fmaf(x3.w, e3.w, acc);
        e0 = n0; e1 = n1; e2 = n2; e3 = n3;
    }
    {
        const int k = 240;
        float4 x0 = *(const float4*)(xs + k);
        float4 x1 = *(const float4*)(xs + k + 4);
        float4 x2 = *(const float4*)(xs + k + 8);
        float4 x3 = *(const float4*)(xs + k + 12);
        acc = fmaf(x0.x, e0.x, acc); acc = fmaf(x0.y, e0.y, acc);
        acc = fmaf(x0.z, e0.z, acc); acc = fmaf(x0.w, e0.w, acc);
        acc = fmaf(x1.x, e1.x, acc); acc = fmaf(x1.y, e1.y, acc);
        acc = fmaf(x1.z, e1.z, acc); acc = fmaf(x1.w, e1.w, acc);
        acc = fmaf(x2.x, e2.x, acc); acc = fmaf(x2.y, e2.y, acc);
        acc = fmaf(x2.z, e2.z, acc); acc = fmaf(x2.w, e2.w, acc);
        acc = fmaf(x3.x, e3.x, acc); acc = fmaf(x3.y, e3.y, acc);
        acc = fmaf(x3.z, e3.z, acc); acc = fmaf(x3.w, e3.w, acc);
    }
    return edc - 2.0 * (double)acc;
}

// ---------------------------------------------------------------------------
// zero per-(row,seg) candidate counts
// ---------------------------------------------------------------------------
__global__ void init_kernel(int* __restrict__ cnt) {
    cnt[blockIdx.x * 256 + threadIdx.x] = 0;
}

// ---------------------------------------------------------------------------
// codebook squared norms: fp64 (selection anchor) + fp32 (MFMA epilogue)
// ---------------------------------------------------------------------------
__global__ void enorm_kernel(const float* __restrict__ embed,
                             double* __restrict__ ed, float* __restrict__ ef) {
    int j = blockIdx.x * 256 + threadIdx.x;
    double s = 0.0;
    for (int d = 0; d < DIM; ++d) {
        double v = (double)embed[(size_t)d * NEMB + j];
        s += v * v;
    }
    ed[j] = s;
    ef[j] = (float)s;
}

// ---------------------------------------------------------------------------
// embed^T fp32 [NEMB][DIM], LDS-tiled transpose (coalesced both sides)
// ---------------------------------------------------------------------------
__global__ void ebt_kernel(const float* __restrict__ embed, float* __restrict__ ebt) {
    __shared__ float t[64][65];
    const int bx = blockIdx.x & 127;   // c-tile
    const int by = blockIdx.x >> 7;    // d-tile (0..3)
    const int tx = threadIdx.x & 63, ty = threadIdx.x >> 6;
#pragma unroll
    for (int i = 0; i < 16; ++i) {
        int d = by * 64 + ty * 16 + i;
        t[ty * 16 + i][tx] = embed[(size_t)d * NEMB + bx * 64 + tx];
    }
    __syncthreads();
#pragma unroll
    for (int i = 0; i < 16; ++i) {
        int c = bx * 64 + ty * 16 + i;
        ebt[(size_t)c * DIM + by * 64 + tx] = t[tx][ty * 16 + i];
    }
}

// ---------------------------------------------------------------------------
// X -> bf16, pre-tiled as the GEMM's LDS A-image
// ---------------------------------------------------------------------------
__global__ void xc_kernel(const float* __restrict__ input,
                          unsigned short* __restrict__ Xc) {
    int tid = blockIdx.x * 256 + threadIdx.x;  // NQ*32 units
    int q = tid >> 5, kcc = tid & 31;
    const float* p = input + (size_t)q * DIM + kcc * 8;
    float4 a = *(const float4*)p;
    float4 b = *(const float4*)(p + 4);
    int mb = q >> 7, mrow = q & 127, kc = kcc >> 3, c = kcc & 7;
    short8 v;
    v[0] = (short)f2bf(a.x); v[1] = (short)f2bf(a.y);
    v[2] = (short)f2bf(a.z); v[3] = (short)f2bf(a.w);
    v[4] = (short)f2bf(b.x); v[5] = (short)f2bf(b.y);
    v[6] = (short)f2bf(b.z); v[7] = (short)f2bf(b.w);
    *(short8*)(Xc + (size_t)((((mb * 4 + kc) * 8) + c) * 128 + mrow) * 8) = v;
}

// ---------------------------------------------------------------------------
// E -> bf16, pre-tiled as the GEMM's LDS B-image
// ---------------------------------------------------------------------------
__global__ void ec_kernel(const float* __restrict__ embed,
                          unsigned short* __restrict__ Ec) {
    int tid = blockIdx.x * 256 + threadIdx.x;  // NEMB*32 units, n fast
    int n = tid & (NEMB - 1), kcc = tid >> 13;
    int nb = n >> 7, nrow = n & 127, kc = kcc >> 3, c = kcc & 7;
    short8 v;
#pragma unroll
    for (int j = 0; j < 8; ++j)
        v[j] = (short)f2bf(embed[(size_t)(kc * 64 + c * 8 + j) * NEMB + n]);
    *(short8*)(Ec + (size_t)((((nb * 4 + kc) * 8) + c) * 128 + nrow) * 8) = v;
}

// ---------------------------------------------------------------------------
// MFMA argmin: block = (mb, seg) owns 128 rows x 2048 codes, running row-min
// in registers, LDS-atomic slot allocation, no global atomics.
// ---------------------------------------------------------------------------
__global__ __launch_bounds__(256, 4) void mfma_argmin_kernel(
    const unsigned short* __restrict__ Xc, const unsigned short* __restrict__ Ec,
    const float* __restrict__ ef, int* __restrict__ cnt,
    unsigned short* __restrict__ cand) {
    __shared__ unsigned short As[8192];  // 16 KB
    __shared__ unsigned short Bs[8192];  // 16 KB
    __shared__ unsigned lcnt[128];

    const int tid = threadIdx.x;
    const int w = tid >> 6, l = tid & 63;
    const int wm = w >> 1, wn = w & 1;
    const int l15 = l & 15, q4 = l >> 4;
    const int mb = blockIdx.x & 255;
    const int seg = blockIdx.x >> 8;

    const unsigned short* xt = Xc + (size_t)mb * 4 * 8192;

    if (tid < 128) lcnt[tid] = 0;

    float rm[4][4];
#pragma unroll
    for (int i = 0; i < 4; ++i)
#pragma unroll
        for (int r = 0; r < 4; ++r) rm[i][r] = 1e30f;

    for (int t16 = 0; t16 < 16; ++t16) {
        const int nb = seg * 16 + t16;
        const unsigned short* et = Ec + (size_t)nb * 4 * 8192;
        const int col0 = nb * 128 + wn * 64 + l15;
        float en[4];
#pragma unroll
        for (int j = 0; j < 4; ++j) en[j] = ef[col0 + 16 * j];

        f32x4 acc[4][4];
#pragma unroll
        for (int i = 0; i < 4; ++i)
#pragma unroll
            for (int j = 0; j < 4; ++j) acc[i][j] = (f32x4){0.f, 0.f, 0.f, 0.f};

        for (int kc = 0; kc < 4; ++kc) {
            __syncthreads();
#pragma unroll
            for (int s = 0; s < 4; ++s) {
                int t = w * 4 + s;
                gll16(xt + kc * 8192 + t * 512 + l * 8, &As[t * 512 + l * 8]);
                gll16(et + kc * 8192 + t * 512 + l * 8, &Bs[t * 512 + l * 8]);
            }
            __syncthreads();
#pragma unroll
            for (int ks = 0; ks < 2; ++ks) {
                short8 af[4], bf[4];
#pragma unroll
                for (int i = 0; i < 4; ++i)
                    af[i] = *(const short8*)&As[((ks * 4 + q4) * 128 + wm * 64 + i * 16 + l15) * 8];
#pragma unroll
                for (int j = 0; j < 4; ++j)
                    bf[j] = *(const short8*)&Bs[((ks * 4 + q4) * 128 + wn * 64 + j * 16 + l15) * 8];
#pragma unroll
                for (int i = 0; i < 4; ++i)
#pragma unroll
                    for (int j = 0; j < 4; ++j)
                        acc[i][j] = __builtin_amdgcn_mfma_f32_16x16x32_bf16(
                            af[i], bf[j], acc[i][j], 0, 0, 0);
            }
        }

#pragma unroll
        for (int i = 0; i < 4; ++i)
#pragma unroll
            for (int j = 0; j < 4; ++j)
#pragma unroll
                for (int r = 0; r < 4; ++r)
                    acc[i][j][r] = en[j] - 2.0f * acc[i][j][r];  // dist~

#pragma unroll
        for (int i = 0; i < 4; ++i)
#pragma unroll
            for (int r = 0; r < 4; ++r) {
                float m = fminf(fminf(acc[i][0][r], acc[i][1][r]),
                                fminf(acc[i][2][r], acc[i][3][r]));
#pragma unroll
                for (int step = 1; step < 16; step <<= 1)
                    m = fminf(m, __shfl_xor(m, step, 64));
                rm[i][r] = fminf(rm[i][r], m);
                const float thr = rm[i][r] + MARGIN;
                const int row128 = wm * 64 + i * 16 + q4 * 4 + r;
#pragma unroll
                for (int j = 0; j < 4; ++j) {
                    if (acc[i][j][r] < thr) {
                        unsigned slot = atomicAdd(&lcnt[row128], 1u);
                        if (slot < CAP_SEG)
                            cand[((size_t)(mb * 128 + row128) * NSEG + seg) * CAP_SEG + slot] =
                                (unsigned short)(col0 + 16 * j);
                    }
                }
            }
    }
    __syncthreads();
    if (tid < 128) cnt[(mb * 128 + tid) * NSEG + seg] = (int)lcnt[tid];
}

// ---------------------------------------------------------------------------
// Rescore: flattened candidate list (one lane per candidate across all segs),
// pipelined loads, bounded per-seg scan fallback on overflow. Bit-exact
// proven-passing metric; smallest-index tie-break. Fused gather + diff.
// ---------------------------------------------------------------------------
__global__ __launch_bounds__(256) void rescore_kernel(
    const float* __restrict__ input, const float* __restrict__ ebt,
    const double* __restrict__ ed, const int* __restrict__ cnt,
    const unsigned short* __restrict__ cand, float* __restrict__ out_q,
    float* __restrict__ out_idx, double* __restrict__ partials) {
    __shared__ float Xs[4][DIM];
    const int w = threadIdx.x >> 6, l = threadIdx.x & 63;
    const int q = blockIdx.x * 4 + w;
    const float* xs = Xs[w];

    float4 xf = *(const float4*)(input + (size_t)q * DIM + 4 * l);
    *(float4*)&Xs[w][4 * l] = xf;
    __syncthreads();

    int m[NSEG];      // candidates usable per seg (0 if overflowed)
    bool ov[NSEG];
#pragma unroll
    for (int s4 = 0; s4 < NSEG; ++s4) {
        int ns = cnt[q * NSEG + s4];
        ov[s4] = (ns > CAP_SEG);
        m[s4] = ov[s4] ? 0 : ns;
    }
    const int off1 = m[0], off2 = m[0] + m[1], off3 = m[0] + m[1] + m[2];
    const int tot = off3 + m[3];

    double bd = 1e300;
    int bc = 0x7FFFFFFF;

    for (int base = 0; base < tot; base += 64) {
        const int idx = base + l;
        if (idx < tot) {
            const int s4 = (idx >= off1) + (idx >= off2) + (idx >= off3);
            const int slot = idx - (s4 == 0 ? 0 : s4 == 1 ? off1
                                        : s4 == 2 ? off2 : off3);
            const int c = cand[((size_t)q * NSEG + s4) * CAP_SEG + slot];
            double d = chain_dist(ebt + (size_t)c * DIM, xs, ed[c]);
            if (d < bd || (d == bd && c < bc)) { bd = d; bc = c; }
        }
    }
#pragma unroll
    for (int s4 = 0; s4 < NSEG; ++s4) {  // bounded fallback: scan only ov segs
        if (ov[s4]) {
            for (int c = s4 * SEG_CODES + l; c < (s4 + 1) * SEG_CODES; c += 64) {
                double d = chain_dist(ebt + (size_t)c * DIM, xs, ed[c]);
                if (d < bd || (d == bd && c < bc)) { bd = d; bc = c; }
            }
        }
    }
#pragma unroll
    for (int off = 1; off < 64; off <<= 1) {
        double od = __shfl_xor(bd, off, 64);
        int oc = __shfl_xor(bc, off, 64);
        if (od < bd || (od == bd && oc < bc)) { bd = od; bc = oc; }
    }

    float4 e4 = *(const float4*)(ebt + (size_t)bc * DIM + 4 * l);
    *(float4*)(out_q + (size_t)q * DIM + 4 * l) = e4;
    float d0 = e4.x - xf.x, d1 = e4.y - xf.y;
    float d2 = e4.z - xf.z, d3 = e4.w - xf.w;
    double dd = (double)d0 * d0 + (double)d1 * d1 +
                (double)d2 * d2 + (double)d3 * d3;
#pragma unroll
    for (int off = 1; off < 64; off <<= 1) dd += __shfl_xor(dd, off, 64);
    if (l == 0) {
        out_idx[q] = (float)bc;
        partials[q] = dd;
    }
}

// ---------------------------------------------------------------------------
// reduce partials -> mean -> diff
// ---------------------------------------------------------------------------
__global__ void diff_kernel(const double* __restrict__ partials,
                            float* __restrict__ out_diff) {
    const int t = threadIdx.x;
    double s = 0.0;
    for (int i = t; i < NQ; i += 256) s += partials[i];
#pragma unroll
    for (int off = 32; off >= 1; off >>= 1) s += __shfl_down(s, off, 64);
    __shared__ double red[4];
    if ((t & 63) == 0) red[t >> 6] = s;
    __syncthreads();
    if (t == 0)
        out_diff[0] = (float)((red[0] + red[1] + red[2] + red[3]) /
                              (double)OUT_Q_ELEMS);
}

extern "C" void kernel_launch(void* const* d_in, const int* in_sizes, int n_in,
                              void* d_out, int out_size, void* d_ws,
                              size_t ws_size, hipStream_t stream) {
    const float* input = (const float*)d_in[0];  // [8,4096,256] fp32
    const float* embed = (const float*)d_in[1];  // [256,8192]  fp32

    float* out_q    = (float*)d_out;             // quantize
    float* out_diff = out_q + OUT_Q_ELEMS;       // diff scalar
    float* out_idx  = out_diff + 1;              // embed_ind (as float)

    char* p = (char*)d_ws;
    unsigned short* Ec  = (unsigned short*)(p);                 //  4 MB
    unsigned short* Xc  = (unsigned short*)(p + 4194304);       // 16 MB
    float*          ebt = (float*)(p + 20971520);               //  8 MB
    double*         ed  = (double*)(p + 29360128);              // 64 KB
    float*          ef  = (float*)(p + 29425664);               // 32 KB
    int*            cnt = (int*)(p + 29458432);                 // 512 KB
    double*         partials = (double*)(p + 29982720);         // 256 KB
    unsigned short* cand = (unsigned short*)(p + 30244864);     //  6 MB

    hipLaunchKernelGGL(init_kernel, dim3(NQ * NSEG / 256), dim3(256), 0, stream,
                       cnt);
    hipLaunchKernelGGL(enorm_kernel, dim3(NEMB / 256), dim3(256), 0, stream,
                       embed, ed, ef);
    hipLaunchKernelGGL(ebt_kernel, dim3((NEMB / 64) * (DIM / 64)), dim3(256),
                       0, stream, embed, ebt);
    hipLaunchKernelGGL(xc_kernel, dim3(NQ * 32 / 256), dim3(256), 0, stream,
                       input, Xc);
    hipLaunchKernelGGL(ec_kernel, dim3(NEMB * 32 / 256), dim3(256), 0, stream,
                       embed, Ec);
    hipLaunchKernelGGL(mfma_argmin_kernel, dim3((NQ / 128) * NSEG), dim3(256),
                       0, stream, Xc, Ec, ef, cnt, cand);
    hipLaunchKernelGGL(rescore_kernel, dim3(NQ / 4), dim3(256), 0, stream,
                       input, ebt, ed, cnt, cand, out_q, out_idx, partials);
    hipLaunchKernelGGL(diff_kernel, dim3(1), dim3(256), 0, stream,
                       partials, out_diff);
}

// Round 6
// 608.470 us; speedup vs baseline: 4.5127x; 1.1668x over previous
//
#include <hip/hip_runtime.h>

#define DIM 256
#define NEMB 8192
#define NQ 32768
#define OUT_Q_ELEMS 8388608   // 8*4096*256
#define NSEG 4
#define SEG_CODES 2048
#define CAP_H 18              // per (row, seg, wn-half) candidate capacity
#define MARGIN 1.0f

typedef __attribute__((ext_vector_type(8))) short short8;
typedef __attribute__((ext_vector_type(4))) float f32x4;
typedef unsigned int u32_as1 __attribute__((address_space(1)));
typedef unsigned int u32_as3 __attribute__((address_space(3)));

// fp32 -> bf16 round-to-nearest-even
__device__ __forceinline__ unsigned short f2bf(float f) {
    unsigned u = __float_as_uint(f);
    u += 0x7FFFu + ((u >> 16) & 1u);
    return (unsigned short)(u >> 16);
}
// async global->LDS, 16B per lane (dest = wave-uniform base + lane*16)
__device__ __forceinline__ void gll16(const void* g, void* l) {
    __builtin_amdgcn_global_load_lds((const u32_as1*)g, (u32_as3*)l, 16, 0, 0);
}

// The EXACT proven-passing metric: fp32 k-ascending single-accumulator fmaf
// chain, dist = ed[c] - 2*(double)dot. 2-deep pipelined 64B loads.
__device__ __forceinline__ double chain_dist(const float* __restrict__ ep,
                                             const float* __restrict__ xs,
                                             double edc) {
    float acc = 0.0f;
    float4 e0 = *(const float4*)(ep);
    float4 e1 = *(const float4*)(ep + 4);
    float4 e2 = *(const float4*)(ep + 8);
    float4 e3 = *(const float4*)(ep + 12);
#pragma unroll
    for (int kk = 0; kk < 15; ++kk) {
        const int k = kk * 16;
        float4 n0 = *(const float4*)(ep + k + 16);
        float4 n1 = *(const float4*)(ep + k + 20);
        float4 n2 = *(const float4*)(ep + k + 24);
        float4 n3 = *(const float4*)(ep + k + 28);
        float4 x0 = *(const float4*)(xs + k);
        float4 x1 = *(const float4*)(xs + k + 4);
        float4 x2 = *(const float4*)(xs + k + 8);
        float4 x3 = *(const float4*)(xs + k + 12);
        acc = fmaf(x0.x, e0.x, acc); acc = fmaf(x0.y, e0.y, acc);
        acc = fmaf(x0.z, e0.z, acc); acc = fmaf(x0.w, e0.w, acc);
        acc = fmaf(x1.x, e1.x, acc); acc = fmaf(x1.y, e1.y, acc);
        acc = fmaf(x1.z, e1.z, acc); acc = fmaf(x1.w, e1.w, acc);
        acc = fmaf(x2.x, e2.x, acc); acc = fmaf(x2.y, e2.y, acc);
        acc = fmaf(x2.z, e2.z, acc); acc = fmaf(x2.w, e2.w, acc);
        acc = fmaf(x3.x, e3.x, acc); acc = fmaf(x3.y, e3.y, acc);
        acc = fmaf(x3.z, e3.z, acc); acc = fmaf(x3.w, e3.w, acc);
        e0 = n0; e1 = n1; e2 = n2; e3 = n3;
    }
    {
        const int k = 240;
        float4 x0 = *(const float4*)(xs + k);
        float4 x1 = *(const float4*)(xs + k + 4);
        float4 x2 = *(const float4*)(xs + k + 8);
        float4 x3 = *(const float4*)(xs + k + 12);
        acc = fmaf(x0.x, e0.x, acc); acc = fmaf(x0.y, e0.y, acc);
        acc = fmaf(x0.z, e0.z, acc); acc = fmaf(x0.w, e0.w, acc);
        acc = fmaf(x1.x, e1.x, acc); acc = fmaf(x1.y, e1.y, acc);
        acc = fmaf(x1.z, e1.z, acc); acc = fmaf(x1.w, e1.w, acc);
        acc = fmaf(x2.x, e2.x, acc); acc = fmaf(x2.y, e2.y, acc);
        acc = fmaf(x2.z, e2.z, acc); acc = fmaf(x2.w, e2.w, acc);
        acc = fmaf(x3.x, e3.x, acc); acc = fmaf(x3.y, e3.y, acc);
        acc = fmaf(x3.z, e3.z, acc); acc = fmaf(x3.w, e3.w, acc);
    }
    return edc - 2.0 * (double)acc;
}

// ---------------------------------------------------------------------------
// Merged prep kernel: block ranges dispatch the 5 independent prep tasks.
//   [0,1024)      zero cnt2 (262144 ints)
//   [1024,1056)   enorm (fp64 + fp32 codebook norms)
//   [1056,1568)   ebt   (embed^T via LDS-tiled transpose)
//   [1568,5664)   xc    (X -> bf16 LDS-image tiles)
//   [5664,6688)   ec    (E -> bf16 LDS-image tiles, transposed)
// ---------------------------------------------------------------------------
__global__ void prep_kernel(const float* __restrict__ input,
                            const float* __restrict__ embed,
                            int* __restrict__ cnt2, double* __restrict__ ed,
                            float* __restrict__ ef, float* __restrict__ ebt,
                            unsigned short* __restrict__ Xc,
                            unsigned short* __restrict__ Ec) {
    __shared__ float t[64][65];
    const int b = blockIdx.x;
    if (b < 1024) {
        cnt2[b * 256 + threadIdx.x] = 0;
    } else if (b < 1056) {
        int j = (b - 1024) * 256 + threadIdx.x;
        double s = 0.0;
        for (int d = 0; d < DIM; ++d) {
            double v = (double)embed[(size_t)d * NEMB + j];
            s += v * v;
        }
        ed[j] = s;
        ef[j] = (float)s;
    } else if (b < 1568) {
        const int bb = b - 1056;
        const int bx = bb & 127, by = bb >> 7;
        const int tx = threadIdx.x & 63, ty = threadIdx.x >> 6;
#pragma unroll
        for (int i = 0; i < 16; ++i) {
            int d = by * 64 + ty * 16 + i;
            t[ty * 16 + i][tx] = embed[(size_t)d * NEMB + bx * 64 + tx];
        }
        __syncthreads();
#pragma unroll
        for (int i = 0; i < 16; ++i) {
            int c = bx * 64 + ty * 16 + i;
            ebt[(size_t)c * DIM + by * 64 + tx] = t[tx][ty * 16 + i];
        }
    } else if (b < 5664) {
        int tid = (b - 1568) * 256 + threadIdx.x;  // NQ*32 units
        int q = tid >> 5, kcc = tid & 31;
        const float* p = input + (size_t)q * DIM + kcc * 8;
        float4 a = *(const float4*)p;
        float4 bv = *(const float4*)(p + 4);
        int mb = q >> 7, mrow = q & 127, kc = kcc >> 3, c = kcc & 7;
        short8 v;
        v[0] = (short)f2bf(a.x);  v[1] = (short)f2bf(a.y);
        v[2] = (short)f2bf(a.z);  v[3] = (short)f2bf(a.w);
        v[4] = (short)f2bf(bv.x); v[5] = (short)f2bf(bv.y);
        v[6] = (short)f2bf(bv.z); v[7] = (short)f2bf(bv.w);
        *(short8*)(Xc + (size_t)((((mb * 4 + kc) * 8) + c) * 128 + mrow) * 8) = v;
    } else {
        int tid = (b - 5664) * 256 + threadIdx.x;  // NEMB*32 units, n fast
        int n = tid & (NEMB - 1), kcc = tid >> 13;
        int nb = n >> 7, nrow = n & 127, kc = kcc >> 3, c = kcc & 7;
        short8 v;
#pragma unroll
        for (int j = 0; j < 8; ++j)
            v[j] = (short)f2bf(embed[(size_t)(kc * 64 + c * 8 + j) * NEMB + n]);
        *(short8*)(Ec + (size_t)((((nb * 4 + kc) * 8) + c) * 128 + nrow) * 8) = v;
    }
}

// ---------------------------------------------------------------------------
// MFMA argmin: block (mb, seg) owns 128 rows x 2048 codes. A-strip (64 KB,
// full K) staged into LDS ONCE; B streamed per-kc (16 KB). Exactly 80 KB LDS
// -> 2 blocks/CU. Candidate slots via atomic-free ballot-prefix allocation:
// each wn-wave owns a private (row,seg,wn) sub-list of CAP_H; per-group
// counts live in uniform registers, stored once at the end.
// ---------------------------------------------------------------------------
__global__ __launch_bounds__(256, 2) void mfma_argmin_kernel(
    const unsigned short* __restrict__ Xc, const unsigned short* __restrict__ Ec,
    const float* __restrict__ ef, int* __restrict__ cnt2,
    unsigned short* __restrict__ cand) {
    __shared__ unsigned short As[32768];  // 64 KB: full-K A strip
    __shared__ unsigned short Bs[8192];   // 16 KB: one kc chunk of B

    const int tid = threadIdx.x;
    const int w = tid >> 6, l = tid & 63;
    const int wm = w >> 1, wn = w & 1;
    const int l15 = l & 15, q4 = l >> 4;
    const int mb = blockIdx.x & 255;   // mb fast: all 4 segs of mb on one XCD
    const int seg = blockIdx.x >> 8;

    const unsigned short* xt = Xc + (size_t)mb * 4 * 8192;

    // ---- stage the whole A strip once (drained by the first Bs barrier)
#pragma unroll
    for (int s = 0; s < 16; ++s) {
        int t = w * 16 + s;
        gll16(xt + t * 512 + l * 8, &As[t * 512 + l * 8]);
    }

    float rm[4][4];      // per-wave (wn-half) running row-min: conservative
    int rcnt[4][4];      // per-(row-group) candidate count, uniform over l15
#pragma unroll
    for (int i = 0; i < 4; ++i)
#pragma unroll
        for (int r = 0; r < 4; ++r) { rm[i][r] = 1e30f; rcnt[i][r] = 0; }

    for (int t16 = 0; t16 < 16; ++t16) {
        const int nb = seg * 16 + t16;
        const unsigned short* et = Ec + (size_t)nb * 4 * 8192;
        const int col0 = nb * 128 + wn * 64 + l15;
        float en[4];
#pragma unroll
        for (int j = 0; j < 4; ++j) en[j] = ef[col0 + 16 * j];  // early issue

        f32x4 acc[4][4];
#pragma unroll
        for (int i = 0; i < 4; ++i)
#pragma unroll
            for (int j = 0; j < 4; ++j) acc[i][j] = (f32x4){0.f, 0.f, 0.f, 0.f};

        for (int kc = 0; kc < 4; ++kc) {
            __syncthreads();
#pragma unroll
            for (int s = 0; s < 4; ++s) {
                int t = w * 4 + s;
                gll16(et + kc * 8192 + t * 512 + l * 8, &Bs[t * 512 + l * 8]);
            }
            __syncthreads();
#pragma unroll
            for (int ks = 0; ks < 2; ++ks) {
                short8 af[4], bf[4];
#pragma unroll
                for (int i = 0; i < 4; ++i)
                    af[i] = *(const short8*)&As[kc * 8192 +
                        ((ks * 4 + q4) * 128 + wm * 64 + i * 16 + l15) * 8];
#pragma unroll
                for (int j = 0; j < 4; ++j)
                    bf[j] = *(const short8*)&Bs[
                        ((ks * 4 + q4) * 128 + wn * 64 + j * 16 + l15) * 8];
#pragma unroll
                for (int i = 0; i < 4; ++i)
#pragma unroll
                    for (int j = 0; j < 4; ++j)
                        acc[i][j] = __builtin_amdgcn_mfma_f32_16x16x32_bf16(
                            af[i], bf[j], acc[i][j], 0, 0, 0);
            }
        }

        // ---- epilogue: dist~, register running-min, ballot-prefix collect
#pragma unroll
        for (int i = 0; i < 4; ++i)
#pragma unroll
            for (int j = 0; j < 4; ++j)
#pragma unroll
                for (int r = 0; r < 4; ++r)
                    acc[i][j][r] = en[j] - 2.0f * acc[i][j][r];  // dist~

#pragma unroll
        for (int i = 0; i < 4; ++i)
#pragma unroll
            for (int r = 0; r < 4; ++r) {
                float m = fminf(fminf(acc[i][0][r], acc[i][1][r]),
                                fminf(acc[i][2][r], acc[i][3][r]));
#pragma unroll
                for (int step = 1; step < 16; step <<= 1)
                    m = fminf(m, __shfl_xor(m, step, 64));  // half-row min
                rm[i][r] = fminf(rm[i][r], m);
                const float thr = rm[i][r] + MARGIN;
                const int row128 = wm * 64 + i * 16 + q4 * 4 + r;
                int base = rcnt[i][r];
#pragma unroll
                for (int j = 0; j < 4; ++j) {
                    const bool cdd = acc[i][j][r] < thr;
                    const unsigned long long mball = __ballot(cdd);
                    const unsigned g =
                        (unsigned)(mball >> (q4 * 16)) & 0xFFFFu;
                    if (cdd) {
                        int slot = base + __popc(g & ((1u << l15) - 1u));
                        if (slot < CAP_H)
                            cand[(((size_t)(mb * 128 + row128) * NSEG + seg) * 2
                                  + wn) * CAP_H + slot] =
                                (unsigned short)(col0 + 16 * j);
                    }
                    base += __popc(g);
                }
                rcnt[i][r] = base;
            }
    }
    // ---- store per-(row,seg,half) counts (uniform over l15 -> lane 0 of group)
    if (l15 == 0) {
#pragma unroll
        for (int i = 0; i < 4; ++i)
#pragma unroll
            for (int r = 0; r < 4; ++r) {
                const int row128 = wm * 64 + i * 16 + q4 * 4 + r;
                cnt2[((mb * 128 + row128) * NSEG + seg) * 2 + wn] = rcnt[i][r];
            }
    }
}

// ---------------------------------------------------------------------------
// Rescore: merge the 8 per-(seg,half) lists; bit-exact proven-passing metric,
// smallest-index tie-break; bounded per-seg scan on overflow. Fused with
// quantize gather + fp64 diff partial. One wave per query.
// ---------------------------------------------------------------------------
__global__ __launch_bounds__(256) void rescore_kernel(
    const float* __restrict__ input, const float* __restrict__ ebt,
    const double* __restrict__ ed, const int* __restrict__ cnt2,
    const unsigned short* __restrict__ cand, float* __restrict__ out_q,
    float* __restrict__ out_idx, double* __restrict__ partials) {
    __shared__ float Xs[4][DIM];
    const int w = threadIdx.x >> 6, l = threadIdx.x & 63;
    const int q = blockIdx.x * 4 + w;
    const float* xs = Xs[w];

    float4 xf = *(const float4*)(input + (size_t)q * DIM + 4 * l);
    *(float4*)&Xs[w][4 * l] = xf;
    __syncthreads();

    int m[8];
    bool segscan[NSEG];
#pragma unroll
    for (int s4 = 0; s4 < NSEG; ++s4) segscan[s4] = false;
#pragma unroll
    for (int li = 0; li < 8; ++li) {
        int ns = cnt2[(q * NSEG + (li >> 1)) * 2 + (li & 1)];
        if (ns > CAP_H) segscan[li >> 1] = true;
        m[li] = ns;
    }
#pragma unroll
    for (int li = 0; li < 8; ++li)
        if (segscan[li >> 1]) m[li] = 0;  // seg scan supersedes its halves

    int tot = 0;
#pragma unroll
    for (int li = 0; li < 8; ++li) tot += m[li];

    double bd = 1e300;
    int bc = 0x7FFFFFFF;

    for (int base = 0; base < tot; base += 64) {
        const int idx = base + l;
        if (idx < tot) {
            int rem = idx, li = 0;
#pragma unroll
            for (int li2 = 0; li2 < 7; ++li2)
                if (rem >= m[li]) { rem -= m[li]; ++li; }
            const int c = cand[((size_t)(q * NSEG + (li >> 1)) * 2 + (li & 1))
                               * CAP_H + rem];
            double d = chain_dist(ebt + (size_t)c * DIM, xs, ed[c]);
            if (d < bd || (d == bd && c < bc)) { bd = d; bc = c; }
        }
    }
#pragma unroll
    for (int s4 = 0; s4 < NSEG; ++s4) {  // bounded fallback on overflow
        if (segscan[s4]) {
            for (int c = s4 * SEG_CODES + l; c < (s4 + 1) * SEG_CODES; c += 64) {
                double d = chain_dist(ebt + (size_t)c * DIM, xs, ed[c]);
                if (d < bd || (d == bd && c < bc)) { bd = d; bc = c; }
            }
        }
    }
#pragma unroll
    for (int off = 1; off < 64; off <<= 1) {
        double od = __shfl_xor(bd, off, 64);
        int oc = __shfl_xor(bc, off, 64);
        if (od < bd || (od == bd && oc < bc)) { bd = od; bc = oc; }
    }

    float4 e4 = *(const float4*)(ebt + (size_t)bc * DIM + 4 * l);
    *(float4*)(out_q + (size_t)q * DIM + 4 * l) = e4;
    float d0 = e4.x - xf.x, d1 = e4.y - xf.y;
    float d2 = e4.z - xf.z, d3 = e4.w - xf.w;
    double dd = (double)d0 * d0 + (double)d1 * d1 +
                (double)d2 * d2 + (double)d3 * d3;
#pragma unroll
    for (int off = 1; off < 64; off <<= 1) dd += __shfl_xor(dd, off, 64);
    if (l == 0) {
        out_idx[q] = (float)bc;
        partials[q] = dd;
    }
}

// ---------------------------------------------------------------------------
// reduce partials -> mean -> diff
// ---------------------------------------------------------------------------
__global__ void diff_kernel(const double* __restrict__ partials,
                            float* __restrict__ out_diff) {
    const int t = threadIdx.x;
    double s = 0.0;
    for (int i = t; i < NQ; i += 256) s += partials[i];
#pragma unroll
    for (int off = 32; off >= 1; off >>= 1) s += __shfl_down(s, off, 64);
    __shared__ double red[4];
    if ((t & 63) == 0) red[t >> 6] = s;
    __syncthreads();
    if (t == 0)
        out_diff[0] = (float)((red[0] + red[1] + red[2] + red[3]) /
                              (double)OUT_Q_ELEMS);
}

extern "C" void kernel_launch(void* const* d_in, const int* in_sizes, int n_in,
                              void* d_out, int out_size, void* d_ws,
                              size_t ws_size, hipStream_t stream) {
    const float* input = (const float*)d_in[0];  // [8,4096,256] fp32
    const float* embed = (const float*)d_in[1];  // [256,8192]  fp32

    float* out_q    = (float*)d_out;             // quantize
    float* out_diff = out_q + OUT_Q_ELEMS;       // diff scalar
    float* out_idx  = out_diff + 1;              // embed_ind (as float)

    char* p = (char*)d_ws;
    unsigned short* Ec  = (unsigned short*)(p);                 //  4 MB
    unsigned short* Xc  = (unsigned short*)(p + 4194304);       // 16 MB
    float*          ebt = (float*)(p + 20971520);               //  8 MB
    double*         ed  = (double*)(p + 29360128);              // 64 KB
    float*          ef  = (float*)(p + 29425664);               // 32 KB
    int*            cnt2 = (int*)(p + 29458432);                //  1 MB
    double*         partials = (double*)(p + 30507008);         // 256 KB
    unsigned short* cand = (unsigned short*)(p + 30769152);     //  9 MB

    hipLaunchKernelGGL(prep_kernel, dim3(6688), dim3(256), 0, stream,
                       input, embed, cnt2, ed, ef, ebt, Xc, Ec);
    hipLaunchKernelGGL(mfma_argmin_kernel, dim3((NQ / 128) * NSEG), dim3(256),
                       0, stream, Xc, Ec, ef, cnt2, cand);
    hipLaunchKernelGGL(rescore_kernel, dim3(NQ / 4), dim3(256), 0, stream,
                       input, ebt, ed, cnt2, cand, out_q, out_idx, partials);
    hipLaunchKernelGGL(diff_kernel, dim3(1), dim3(256), 0, stream,
                       partials, out_diff);
}